// Round 10
// baseline (978.849 us; speedup 1.0000x reference)
//
#include <hip/hip_runtime.h>
#include <math.h>
#include <float.h>

#define B_   16
#define N_   4096
#define CIN  3
#define COUT 64
#define KNN  20
#define EPS_ 1e-5

// ---------------------------------------------------------------------------
// Workspace layout:
//   [0,   216): double stats[27]    (Sum e[6], Sum e e^T upper-tri[21])
//   [256, 768): float scale[64], shift[64]
//   [1024, 1024 + B*N*KNN*4): int idx[B*N*KNN]           (5242880 B)
//   [5243904, +B*N*4): int perm[B*N]  (Morton row order)  (262144 B)
// ---------------------------------------------------------------------------

__device__ __forceinline__ unsigned expand10(unsigned v) {
    v = (v | (v << 16)) & 0x030000FFu;
    v = (v | (v << 8))  & 0x0300F00Fu;
    v = (v | (v << 4))  & 0x030C30C3u;
    v = (v | (v << 2))  & 0x09249249u;
    return v;
}
__device__ __forceinline__ unsigned quant10(float v) {
    int q = (int)((v + 4.0f) * 128.0f);
    return (unsigned)min(1023, max(0, q));
}

// ===========================================================================
// Kernel 0: per-batch Morton COUNTING sort (1024 buckets = top 10 morton
// bits). PERFORMANCE ONLY: any permutation is correctness-neutral.
// ===========================================================================
__global__ __launch_bounds__(1024) void morton_bucket_kernel(
    const float* __restrict__ x, int* __restrict__ perm)
{
    __shared__ int hist[1024];
    __shared__ int scanbuf[1024];
    __shared__ int offs[1024];
    const int b = blockIdx.x, tid = threadIdx.x;
    const float* xb = x + (size_t)b * N_ * CIN;

    hist[tid] = 0;
    __syncthreads();

    int keys[4];
#pragma unroll
    for (int i = 0; i < 4; ++i) {
        int p = tid + i * 1024;
        float v0 = xb[p * 3 + 0], v1 = xb[p * 3 + 1], v2 = xb[p * 3 + 2];
        unsigned m = (expand10(quant10(v0)) << 2) |
                     (expand10(quant10(v1)) << 1) |
                      expand10(quant10(v2));
        keys[i] = (int)(m >> 20);          // top 10 bits
        atomicAdd(&hist[keys[i]], 1);
    }
    __syncthreads();

    int v = hist[tid];
    scanbuf[tid] = v;
    __syncthreads();
    for (int off = 1; off < 1024; off <<= 1) {   // Hillis-Steele inclusive
        int t = (tid >= off) ? scanbuf[tid - off] : 0;
        __syncthreads();
        scanbuf[tid] += t;
        __syncthreads();
    }
    offs[tid] = scanbuf[tid] - v;                // exclusive base
    __syncthreads();

#pragma unroll
    for (int i = 0; i < 4; ++i) {
        int p = tid + i * 1024;
        int pos = atomicAdd(&offs[keys[i]], 1);
        perm[b * N_ + pos] = p;
    }
}

// ===========================================================================
// Kernel 1: exact-match KNN (top-20, jax top_k semantics) + BN stats.
// Distance: fp32 EXPANSION form, bit-identical to np ref (verified r3-r9).
// Selection: 20 smallest u64 keys (sortable_fp32(d)<<32 | orig_j) — exact
// top_k with lowest-index tie-break, independent of visit order / partition.
//
// Round-10: fixed threshold tau (EXACT) + sentinel heap.
//   r9 measured: 92 instr/cand, trigger f=0.55 — per-lane inserts (~25-35)
//   x 64 lanes over 256 groups saturate the wave-union. Fix the event count:
//   tau = 20th-smallest distance over 24 morton-adjacent candidates of the
//   FULL array (per lane, branchless 5-max heap -> min = 20th of 24).
//   Monotonicity: kth-smallest of a subset >= kth-smallest of the full set,
//   so tau >= true 20th-NN distance -> rejecting d>tau can never discard a
//   true top-20 member. Acceptance bound ab = min(worst, tauk) where
//   tauk = pack(tau, idx=0xFFFFFFFF) (>= any real key with d<=tau).
//   Eviction-safety: a discarded member would need 20 better quarter-mates,
//   contradicting full-top-20 membership. tau is per-ROW (identical across
//   the 4 quarter-waves: same ball, same arithmetic) -> merge consistent.
//   No prefill: slots start as distinct sentinels > tauk; ab=tauk from the
//   first candidate (no warmup insert storm). Group-4 loads (ILP) with
//   group-2 trigger checks (finer storm granularity).
// ===========================================================================
__global__ __launch_bounds__(512) void knn_tau_kernel(
    const float* __restrict__ x, const int* __restrict__ perm,
    int* __restrict__ idx_out, double* __restrict__ stats)
{
    __shared__ __align__(16) char smem[65536];
    float4* pts = (float4*)smem;                         // {x,y,z,bitcast(j)}
    unsigned long long* scr = (unsigned long long*)smem; // merge-scratch view

    const int b    = blockIdx.y;
    const int tid  = threadIdx.x;
    const int wave = tid >> 6;
    const int lane = tid & 63;
    const int r    = wave >> 2;     // row-group 0..1
    const int q    = wave & 3;      // interleave class: positions p&3==q
    const float* xb = x + (size_t)b * N_ * CIN;

    // stage in MORTON order: pts[pos] = {x,y,z, bits(orig_j)}
    for (int p = tid; p < N_; p += 512) {
        int j = perm[b * N_ + p];                        // coalesced
        pts[p] = make_float4(xb[j * 3 + 0], xb[j * 3 + 1], xb[j * 3 + 2],
                             __int_as_float(j));
    }
    __syncthreads();

    // rows: morton positions; orig row index from .w
    const int rowg = blockIdx.x * 128 + r * 64;          // wave's first row pos
    const float4 xf = pts[rowg + lane];
    const int jrow  = __float_as_int(xf.w);
    const float sqi = __fadd_rn(__fadd_rn(__fmul_rn(xf.x, xf.x),
                                          __fmul_rn(xf.y, xf.y)),
                                __fmul_rn(xf.z, xf.z));

    auto mkd = [&](float4 p) -> float {
        float sqj = __fadd_rn(__fadd_rn(__fmul_rn(p.x, p.x),
                                        __fmul_rn(p.y, p.y)),
                              __fmul_rn(p.z, p.z));
        float dot = __fadd_rn(__fadd_rn(__fmul_rn(xf.x, p.x),
                                        __fmul_rn(xf.y, p.y)),
                              __fmul_rn(xf.z, p.z));
        return __fsub_rn(__fadd_rn(sqi, sqj), __fmul_rn(2.0f, dot));
    };
    auto packkey = [&](float d, int j) -> unsigned long long {
        unsigned u = __float_as_uint(d);
        unsigned s = u ^ (0x80000000u | (unsigned)((int)u >> 31));
        return ((unsigned long long)s << 32) | (unsigned)j;
    };
    auto mkkey = [&](float4 p) -> unsigned long long {
        return packkey(mkd(p), __float_as_int(p.w));
    };

    // --- tau pass: 20th smallest of 24 FULL-array morton-ball candidates
    // (= min of the 5 largest). Branchless; per-lane divergent LDS reads.
    const int ballbase = rowg + lane - 12;
    float t5[5];
#pragma unroll
    for (int k = 0; k < 5; ++k)
        t5[k] = mkd(pts[(ballbase + k) & (N_ - 1)]);
    float tmin = fminf(fminf(fminf(t5[0], t5[1]), fminf(t5[2], t5[3])), t5[4]);
#pragma unroll
    for (int k = 5; k < 24; ++k) {
        float d = mkd(pts[(ballbase + k) & (N_ - 1)]);
        bool ins = d > tmin;   // dup-tmin double-replace only loosens tau: safe
#pragma unroll
        for (int s2 = 0; s2 < 5; ++s2)
            t5[s2] = (ins && t5[s2] == tmin) ? d : t5[s2];
        tmin = fminf(fminf(fminf(t5[0], t5[1]), fminf(t5[2], t5[3])), t5[4]);
    }
    const unsigned long long tauk = packkey(tmin, -1);

    // sentinel-initialized heap; acceptance bound ab = min(worst, tauk)
    unsigned long long bk[KNN];
#pragma unroll
    for (int k = 0; k < KNN; ++k) bk[k] = ~0ull - (unsigned long long)k;
    unsigned long long worst = ~0ull;
    unsigned long long ab    = tauk;

    // replace-by-value insert: keys unique -> exactly one slot matches worst
    auto insert = [&](unsigned long long key) {
        if (key < ab) {
            unsigned long long oldw = worst, nw = 0;
#pragma unroll
            for (int k = 0; k < KNN; ++k) {
                bk[k] = (bk[k] == oldw) ? key : bk[k];
                nw = bk[k] > nw ? bk[k] : nw;
            }
            worst = nw;
            ab = nw < tauk ? nw : tauk;
        }
    };

    // shuffled full scan of the quarter: v=(s*509)&1023 is a bijection.
    const int ta = rowg >> 2;            // wave-uniform anchor (SGPR math)
    for (int s = 0; s < 1024; s += 4) {
        int v0 = ((s + 0) * 509) & 1023;
        int v1 = ((s + 1) * 509) & 1023;
        int v2 = ((s + 2) * 509) & 1023;
        int v3 = ((s + 3) * 509) & 1023;
        float4 a0 = pts[4 * ((ta + v0) & 1023) + q];
        float4 a1 = pts[4 * ((ta + v1) & 1023) + q];
        float4 a2 = pts[4 * ((ta + v2) & 1023) + q];
        float4 a3 = pts[4 * ((ta + v3) & 1023) + q];
        unsigned long long k0 = mkkey(a0);
        unsigned long long k1 = mkkey(a1);
        unsigned long long k2 = mkkey(a2);
        unsigned long long k3 = mkkey(a3);
        if ((k0 < ab) | (k1 < ab)) { insert(k0); insert(k1); }
        if ((k2 < ab) | (k3 < ab)) { insert(k2); insert(k3); }
    }
    __syncthreads();    // scans done; pts dead (xf in regs) -> scr valid

    // merge round A: q1 -> slot0, q3 -> slot1   (40KB <= 64KB)
    // incoming real keys are < tauk (same per-row tau) -> ab filter exact;
    // incoming sentinels are > tauk -> correctly rejected.
    if (q & 1) {
        int base = ((r * 2 + (q >> 1)) * 64 + lane) * KNN;
#pragma unroll
        for (int k = 0; k < KNN; ++k) scr[base + k] = bk[k];
    }
    __syncthreads();
    if (!(q & 1)) {                 // q0 absorbs q1; q2 absorbs q3
        int base = ((r * 2 + (q >> 1)) * 64 + lane) * KNN;
#pragma unroll
        for (int k = 0; k < KNN; ++k) insert(scr[base + k]);
    }
    __syncthreads();
    // merge round B: q2 -> slot1; q0 absorbs
    if (q == 2) {
        int base = ((r * 2 + 1) * 64 + lane) * KNN;
#pragma unroll
        for (int k = 0; k < KNN; ++k) scr[base + k] = bk[k];
    }
    __syncthreads();
    if (q == 0) {
        int base = ((r * 2 + 1) * 64 + lane) * KNN;
#pragma unroll
        for (int k = 0; k < KNN; ++k) insert(scr[base + k]);

        const long long row = (long long)b * N_ + jrow;
        int bi[KNN];
#pragma unroll
        for (int k = 0; k < KNN; ++k) bi[k] = (int)(bk[k] & 0xFFFFFFFFull);
#pragma unroll
        for (int k = 0; k < KNN; ++k) idx_out[row * KNN + k] = bi[k];

        // --- BN statistics (neighbor coords from global; batch slab is hot)
        float acc[27];
#pragma unroll
        for (int t = 0; t < 27; ++t) acc[t] = 0.0f;
#pragma unroll
        for (int k = 0; k < KNN; ++k) {
            const float* pj = xb + bi[k] * 3;
            float e[6] = { xf.x, xf.y, xf.z,
                           pj[0] - xf.x, pj[1] - xf.y, pj[2] - xf.z };
            int t = 6;
#pragma unroll
            for (int a = 0; a < 6; ++a) {
                acc[a] += e[a];
#pragma unroll
                for (int bb = a; bb < 6; ++bb) acc[t++] += e[a] * e[bb];
            }
        }
#pragma unroll
        for (int t = 0; t < 27; ++t) {
            float v = acc[t];
            v += __shfl_down(v, 32); v += __shfl_down(v, 16);
            v += __shfl_down(v, 8);  v += __shfl_down(v, 4);
            v += __shfl_down(v, 2);  v += __shfl_down(v, 1);
            acc[t] = v;
        }
        if (lane == 0) {
#pragma unroll
            for (int t = 0; t < 27; ++t) atomicAdd(&stats[t], (double)acc[t]);
        }
    }
}

// ===========================================================================
// Kernel 2: fold stats -> per-channel scale/shift (fp64, 64 threads)
// ===========================================================================
__global__ void bn_prep_kernel(
    const double* __restrict__ stats,
    const float* __restrict__ w1, const float* __restrict__ b1,
    const float* __restrict__ gamma, const float* __restrict__ beta,
    float* __restrict__ scale_shift)
{
    const int c = threadIdx.x;
    double s[6], S[6][6];
#pragma unroll
    for (int a = 0; a < 6; ++a) s[a] = stats[a];
    int t = 6;
#pragma unroll
    for (int a = 0; a < 6; ++a)
#pragma unroll
        for (int bb = a; bb < 6; ++bb) { S[a][bb] = stats[t]; S[bb][a] = stats[t]; ++t; }

    const double M = (double)B_ * N_ * KNN;
    double wc[6];
#pragma unroll
    for (int j = 0; j < 6; ++j) wc[j] = (double)w1[j * COUT + c];
    const double b1c = (double)b1[c];

    double sw = 0.0;
#pragma unroll
    for (int j = 0; j < 6; ++j) sw += s[j] * wc[j];
    double mean = sw / M + b1c;

    double qq = 0.0;
#pragma unroll
    for (int a = 0; a < 6; ++a)
#pragma unroll
        for (int bb = 0; bb < 6; ++bb) qq += S[a][bb] * wc[a] * wc[bb];
    double ex2 = (qq + 2.0 * b1c * sw) / M + b1c * b1c;
    double var = ex2 - mean * mean;

    double sc = (double)gamma[c] / sqrt(var + (double)EPS_);
    double sh = (double)beta[c] - mean * sc;
    scale_shift[c]        = (float)sc;
    scale_shift[COUT + c] = (float)sh;
}

// ===========================================================================
// Kernel 3: fused edge-feature -> lin1 -> BN -> ReLU -> lin2 -> max over K.
// 8 rows per wave; rows processed in pairs packed [k][d][pair] in LDS.
// ===========================================================================
__global__ __launch_bounds__(256) void mlp_max_kernel(
    const float* __restrict__ x, const int* __restrict__ idx,
    const float* __restrict__ w1, const float* __restrict__ b1,
    const float* __restrict__ scale_shift,
    const float* __restrict__ w2, const float* __restrict__ b2,
    float* __restrict__ out)
{
    __shared__ __align__(16) float h2[4][KNN][COUT][2];   // 40 KB

    const int tid = threadIdx.x;
    const int wv  = tid >> 6;
    const int c   = tid & 63;

    float w1c[6];
#pragma unroll
    for (int j = 0; j < 6; ++j) w1c[j] = w1[j * COUT + c];
    const float b1c = b1[c];
    const float sc  = scale_shift[c];
    const float sh  = scale_shift[COUT + c];
    const float b2c = b2[c];
    float w2c[COUT];
#pragma unroll
    for (int d = 0; d < COUT; ++d) w2c[d] = w2[d * COUT + c];

    const int rowbase = (blockIdx.x * 4 + wv) * 8;

    for (int pair = 0; pair < 4; ++pair) {
        const int ra = rowbase + pair * 2;
#pragma unroll
        for (int rr = 0; rr < 2; ++rr) {
            const int row = ra + rr;
            const int b   = row >> 12;
            const float xi0 = x[row * 3 + 0];
            const float xi1 = x[row * 3 + 1];
            const float xi2 = x[row * 3 + 2];
#pragma unroll
            for (int k = 0; k < KNN; ++k) {
                int j = idx[row * KNN + k];               // wave-uniform
                const float* pj = x + ((size_t)b * N_ + j) * 3;
                float e3 = pj[0] - xi0, e4 = pj[1] - xi1, e5 = pj[2] - xi2;
                float h = b1c;
                h = fmaf(xi0, w1c[0], h); h = fmaf(xi1, w1c[1], h);
                h = fmaf(xi2, w1c[2], h); h = fmaf(e3,  w1c[3], h);
                h = fmaf(e4,  w1c[4], h); h = fmaf(e5,  w1c[5], h);
                h = fmaf(h, sc, sh);
                h2[wv][k][c][rr] = fmaxf(h, 0.0f);        // 2-way bank alias: free
            }
        }
        __syncthreads();   // uniform across the block's 4 waves

        float mxa = -INFINITY, mxb = -INFINITY;
        for (int k = 0; k < KNN; ++k) {
            float aa = b2c, ab = b2c;
#pragma unroll
            for (int d2 = 0; d2 < COUT / 2; ++d2) {
                float4 hv = *(const float4*)&h2[wv][k][d2 * 2][0]; // broadcast
                aa = fmaf(hv.x, w2c[d2 * 2 + 0], aa);
                ab = fmaf(hv.y, w2c[d2 * 2 + 0], ab);
                aa = fmaf(hv.z, w2c[d2 * 2 + 1], aa);
                ab = fmaf(hv.w, w2c[d2 * 2 + 1], ab);
            }
            mxa = fmaxf(mxa, aa); mxb = fmaxf(mxb, ab);
        }
        out[(size_t)ra * COUT + c]       = mxa;
        out[(size_t)(ra + 1) * COUT + c] = mxb;
        __syncthreads();   // protect h2 reuse next pair
    }
}

// ===========================================================================
extern "C" void kernel_launch(void* const* d_in, const int* in_sizes, int n_in,
                              void* d_out, int out_size, void* d_ws, size_t ws_size,
                              hipStream_t stream)
{
    const float* x     = (const float*)d_in[0];
    const float* w1    = (const float*)d_in[2];
    const float* b1    = (const float*)d_in[3];
    const float* gamma = (const float*)d_in[4];
    const float* beta  = (const float*)d_in[5];
    const float* w2    = (const float*)d_in[6];
    const float* b2    = (const float*)d_in[7];
    float* out = (float*)d_out;

    char*   ws          = (char*)d_ws;
    double* stats       = (double*)ws;
    float*  scale_shift = (float*)(ws + 256);
    int*    idx         = (int*)(ws + 1024);
    int*    perm        = (int*)(ws + 1024 + (size_t)B_ * N_ * KNN * 4);

    hipMemsetAsync(stats, 0, 27 * sizeof(double), stream);
    morton_bucket_kernel<<<B_, 1024, 0, stream>>>(x, perm);
    knn_tau_kernel<<<dim3(32, 16), 512, 0, stream>>>(x, perm, idx, stats);
    bn_prep_kernel<<<1, COUT, 0, stream>>>(stats, w1, b1, gamma, beta, scale_shift);
    mlp_max_kernel<<<(B_ * N_) / 32, 256, 0, stream>>>(x, idx, w1, b1, scale_shift,
                                                       w2, b2, out);
}

// Round 11
// 756.383 us; speedup vs baseline: 1.2941x; 1.2941x over previous
//
#include <hip/hip_runtime.h>
#include <math.h>
#include <float.h>

#define B_   16
#define N_   4096
#define CIN  3
#define COUT 64
#define KNN  20
#define EPS_ 1e-5

// ---------------------------------------------------------------------------
// Workspace layout:
//   [0,   216): double stats[27]    (Sum e[6], Sum e e^T upper-tri[21])
//   [256, 768): float scale[64], shift[64]
//   [1024, 1024 + B*N*KNN*4): int idx[B*N*KNN]           (5242880 B)
//   [5243904, +B*N*4): int perm[B*N]  (Morton row order)  (262144 B)
// ---------------------------------------------------------------------------

__device__ __forceinline__ unsigned expand10(unsigned v) {
    v = (v | (v << 16)) & 0x030000FFu;
    v = (v | (v << 8))  & 0x0300F00Fu;
    v = (v | (v << 4))  & 0x030C30C3u;
    v = (v | (v << 2))  & 0x09249249u;
    return v;
}
__device__ __forceinline__ unsigned quant10(float v) {
    int q = (int)((v + 4.0f) * 128.0f);
    return (unsigned)min(1023, max(0, q));
}

// ===========================================================================
// Kernel 0: per-batch Morton COUNTING sort (1024 buckets = top 10 morton
// bits). PERFORMANCE ONLY: any permutation is correctness-neutral.
// ===========================================================================
__global__ __launch_bounds__(1024) void morton_bucket_kernel(
    const float* __restrict__ x, int* __restrict__ perm)
{
    __shared__ int hist[1024];
    __shared__ int scanbuf[1024];
    __shared__ int offs[1024];
    const int b = blockIdx.x, tid = threadIdx.x;
    const float* xb = x + (size_t)b * N_ * CIN;

    hist[tid] = 0;
    __syncthreads();

    int keys[4];
#pragma unroll
    for (int i = 0; i < 4; ++i) {
        int p = tid + i * 1024;
        float v0 = xb[p * 3 + 0], v1 = xb[p * 3 + 1], v2 = xb[p * 3 + 2];
        unsigned m = (expand10(quant10(v0)) << 2) |
                     (expand10(quant10(v1)) << 1) |
                      expand10(quant10(v2));
        keys[i] = (int)(m >> 20);          // top 10 bits
        atomicAdd(&hist[keys[i]], 1);
    }
    __syncthreads();

    int v = hist[tid];
    scanbuf[tid] = v;
    __syncthreads();
    for (int off = 1; off < 1024; off <<= 1) {   // Hillis-Steele inclusive
        int t = (tid >= off) ? scanbuf[tid - off] : 0;
        __syncthreads();
        scanbuf[tid] += t;
        __syncthreads();
    }
    offs[tid] = scanbuf[tid] - v;                // exclusive base
    __syncthreads();

#pragma unroll
    for (int i = 0; i < 4; ++i) {
        int p = tid + i * 1024;
        int pos = atomicAdd(&offs[keys[i]], 1);
        perm[b * N_ + pos] = p;
    }
}

// ===========================================================================
// Kernel 1: exact-match KNN (top-20, jax top_k semantics) + BN stats.
// Distance: fp32 EXPANSION form, bit-identical to np ref (verified r3-r10).
//
// Round-11 heap: F64-PACKED KEYS + SORTED-SHIFT INSERT.
//   key = fma((double)sortable_u32(d), 4096.0, (double)j): exact integers
//   < 2^44 < 2^53, so f64 ordering == (d, j) lexicographic == the verified
//   u64-key ordering (top_k lowest-index tie-break). Selection = 20 smallest
//   keys, independent of visit order / wave partition (merge = union).
//   Heap array kept ASCENDING-SORTED; insert = 20-step carry chain of
//   fmin/fmax f64 (single-instr each, ~40 ops) vs the old ~160-instr u64
//   replace+rescan body. worst = bk[19], free.
//   r9/r10 evidence: per-lane insert events (>=10) saturate the 64-lane
//   union trigger (f~0.55) regardless of scan order or tau-threshold, so
//   the ONLY remaining lever is the cost of the triggered body.
// Structure otherwise byte-identical to r9 (475us measured): morton staging,
// mod-4 interleaved quarters, ball prefill, 509-stride shuffled scan,
// 2-round LDS merge, BN stats.
// ===========================================================================
__global__ __launch_bounds__(512) void knn_f64_kernel(
    const float* __restrict__ x, const int* __restrict__ perm,
    int* __restrict__ idx_out, double* __restrict__ stats)
{
    __shared__ __align__(16) char smem[65536];
    float4* pts = (float4*)smem;                 // {x,y,z,bitcast(j)}
    double* scr = (double*)smem;                 // merge-scratch view

    const int b    = blockIdx.y;
    const int tid  = threadIdx.x;
    const int wave = tid >> 6;
    const int lane = tid & 63;
    const int r    = wave >> 2;     // row-group 0..1
    const int q    = wave & 3;      // interleave class: positions p&3==q
    const float* xb = x + (size_t)b * N_ * CIN;

    // stage in MORTON order: pts[pos] = {x,y,z, bits(orig_j)}
    for (int p = tid; p < N_; p += 512) {
        int j = perm[b * N_ + p];                // coalesced
        pts[p] = make_float4(xb[j * 3 + 0], xb[j * 3 + 1], xb[j * 3 + 2],
                             __int_as_float(j));
    }
    __syncthreads();

    // rows: morton positions; orig row index from .w
    const int rowg = blockIdx.x * 128 + r * 64;  // wave's first row pos
    const float4 xf = pts[rowg + lane];
    const int jrow  = __float_as_int(xf.w);
    const float sqi = __fadd_rn(__fadd_rn(__fmul_rn(xf.x, xf.x),
                                          __fmul_rn(xf.y, xf.y)),
                                __fmul_rn(xf.z, xf.z));

    auto mkkey = [&](float4 p) -> double {
        float sqj = __fadd_rn(__fadd_rn(__fmul_rn(p.x, p.x),
                                        __fmul_rn(p.y, p.y)),
                              __fmul_rn(p.z, p.z));
        float dot = __fadd_rn(__fadd_rn(__fmul_rn(xf.x, p.x),
                                        __fmul_rn(xf.y, p.y)),
                              __fmul_rn(xf.z, p.z));
        float d = __fsub_rn(__fadd_rn(sqi, sqj), __fmul_rn(2.0f, dot));
        unsigned u = __float_as_uint(d);
        unsigned s = u ^ (0x80000000u | (unsigned)((int)u >> 31));
        return fma((double)s, 4096.0,
                   (double)(unsigned)__float_as_int(p.w));
    };

    double bk[KNN];
#pragma unroll
    for (int k = 0; k < KNN; ++k) bk[k] = 1e300;     // sentinels (sorted)

    // sorted-shift insert: bk stays ascending; bk'[i]=min(max(bk[i-1],key),bk[i])
    auto insert = [&](double key) {
        if (key < bk[KNN - 1]) {
            double m = key;                  // carries max(bk_old[i-1], key)
#pragma unroll
            for (int k = 0; k < KNN; ++k) {
                double old = bk[k];
                bk[k] = fmin(m, old);
                m     = fmax(old, m);
            }
        }
    };

    // ball prefill: 20 morton-adjacent quarter candidates -> tight bk[19]
    const int ta = rowg >> 2;            // wave-uniform anchor (SGPR math)
#pragma unroll
    for (int k = 0; k < KNN; ++k)
        insert(mkkey(pts[4 * ((ta + k) & 1023) + q]));

    // shuffled scan: v=(s*509)&1023 is a bijection on [0,1024);
    // v<20 are the prefill t-offsets -> masked with sentinel (never inserts).
    for (int s = 0; s < 1024; s += 4) {
        int v0 = ((s + 0) * 509) & 1023;
        int v1 = ((s + 1) * 509) & 1023;
        int v2 = ((s + 2) * 509) & 1023;
        int v3 = ((s + 3) * 509) & 1023;
        float4 a0 = pts[4 * ((ta + v0) & 1023) + q];
        float4 a1 = pts[4 * ((ta + v1) & 1023) + q];
        float4 a2 = pts[4 * ((ta + v2) & 1023) + q];
        float4 a3 = pts[4 * ((ta + v3) & 1023) + q];
        double k0 = (v0 < 20) ? 1e300 : mkkey(a0);
        double k1 = (v1 < 20) ? 1e300 : mkkey(a1);
        double k2 = (v2 < 20) ? 1e300 : mkkey(a2);
        double k3 = (v3 < 20) ? 1e300 : mkkey(a3);
        double w = bk[KNN - 1];          // stale for the check: over-enters only
        if ((k0 < w) | (k1 < w) | (k2 < w) | (k3 < w)) {
            insert(k0); insert(k1); insert(k2); insert(k3);
        }
    }
    __syncthreads();    // scans done; pts dead (xf in regs) -> scr valid

    // merge round A: q1 -> slot0, q3 -> slot1   (40KB <= 64KB)
    if (q & 1) {
        int base = ((r * 2 + (q >> 1)) * 64 + lane) * KNN;
#pragma unroll
        for (int k = 0; k < KNN; ++k) scr[base + k] = bk[k];
    }
    __syncthreads();
    if (!(q & 1)) {                 // q0 absorbs q1; q2 absorbs q3
        int base = ((r * 2 + (q >> 1)) * 64 + lane) * KNN;
#pragma unroll
        for (int k = 0; k < KNN; ++k) insert(scr[base + k]);
    }
    __syncthreads();
    // merge round B: q2 -> slot1; q0 absorbs
    if (q == 2) {
        int base = ((r * 2 + 1) * 64 + lane) * KNN;
#pragma unroll
        for (int k = 0; k < KNN; ++k) scr[base + k] = bk[k];
    }
    __syncthreads();
    if (q == 0) {
        int base = ((r * 2 + 1) * 64 + lane) * KNN;
#pragma unroll
        for (int k = 0; k < KNN; ++k) insert(scr[base + k]);

        const long long row = (long long)b * N_ + jrow;
        int bi[KNN];
#pragma unroll
        for (int k = 0; k < KNN; ++k) {
            // exact extraction: key = s*4096 + j, both < 2^53
            double sp = trunc(bk[k] * (1.0 / 4096.0));
            bi[k] = (int)(bk[k] - sp * 4096.0);
        }
#pragma unroll
        for (int k = 0; k < KNN; ++k) idx_out[row * KNN + k] = bi[k];

        // --- BN statistics (neighbor coords from global; batch slab is hot)
        float acc[27];
#pragma unroll
        for (int t = 0; t < 27; ++t) acc[t] = 0.0f;
#pragma unroll
        for (int k = 0; k < KNN; ++k) {
            const float* pj = xb + bi[k] * 3;
            float e[6] = { xf.x, xf.y, xf.z,
                           pj[0] - xf.x, pj[1] - xf.y, pj[2] - xf.z };
            int t = 6;
#pragma unroll
            for (int a = 0; a < 6; ++a) {
                acc[a] += e[a];
#pragma unroll
                for (int bb = a; bb < 6; ++bb) acc[t++] += e[a] * e[bb];
            }
        }
#pragma unroll
        for (int t = 0; t < 27; ++t) {
            float v = acc[t];
            v += __shfl_down(v, 32); v += __shfl_down(v, 16);
            v += __shfl_down(v, 8);  v += __shfl_down(v, 4);
            v += __shfl_down(v, 2);  v += __shfl_down(v, 1);
            acc[t] = v;
        }
        if (lane == 0) {
#pragma unroll
            for (int t = 0; t < 27; ++t) atomicAdd(&stats[t], (double)acc[t]);
        }
    }
}

// ===========================================================================
// Kernel 2: fold stats -> per-channel scale/shift (fp64, 64 threads)
// ===========================================================================
__global__ void bn_prep_kernel(
    const double* __restrict__ stats,
    const float* __restrict__ w1, const float* __restrict__ b1,
    const float* __restrict__ gamma, const float* __restrict__ beta,
    float* __restrict__ scale_shift)
{
    const int c = threadIdx.x;
    double s[6], S[6][6];
#pragma unroll
    for (int a = 0; a < 6; ++a) s[a] = stats[a];
    int t = 6;
#pragma unroll
    for (int a = 0; a < 6; ++a)
#pragma unroll
        for (int bb = a; bb < 6; ++bb) { S[a][bb] = stats[t]; S[bb][a] = stats[t]; ++t; }

    const double M = (double)B_ * N_ * KNN;
    double wc[6];
#pragma unroll
    for (int j = 0; j < 6; ++j) wc[j] = (double)w1[j * COUT + c];
    const double b1c = (double)b1[c];

    double sw = 0.0;
#pragma unroll
    for (int j = 0; j < 6; ++j) sw += s[j] * wc[j];
    double mean = sw / M + b1c;

    double qq = 0.0;
#pragma unroll
    for (int a = 0; a < 6; ++a)
#pragma unroll
        for (int bb = 0; bb < 6; ++bb) qq += S[a][bb] * wc[a] * wc[bb];
    double ex2 = (qq + 2.0 * b1c * sw) / M + b1c * b1c;
    double var = ex2 - mean * mean;

    double sc = (double)gamma[c] / sqrt(var + (double)EPS_);
    double sh = (double)beta[c] - mean * sc;
    scale_shift[c]        = (float)sc;
    scale_shift[COUT + c] = (float)sh;
}

// ===========================================================================
// Kernel 3: fused edge-feature -> lin1 -> BN -> ReLU -> lin2 -> max over K.
// 8 rows per wave; rows processed in pairs packed [k][d][pair] in LDS.
// ===========================================================================
__global__ __launch_bounds__(256) void mlp_max_kernel(
    const float* __restrict__ x, const int* __restrict__ idx,
    const float* __restrict__ w1, const float* __restrict__ b1,
    const float* __restrict__ scale_shift,
    const float* __restrict__ w2, const float* __restrict__ b2,
    float* __restrict__ out)
{
    __shared__ __align__(16) float h2[4][KNN][COUT][2];   // 40 KB

    const int tid = threadIdx.x;
    const int wv  = tid >> 6;
    const int c   = tid & 63;

    float w1c[6];
#pragma unroll
    for (int j = 0; j < 6; ++j) w1c[j] = w1[j * COUT + c];
    const float b1c = b1[c];
    const float sc  = scale_shift[c];
    const float sh  = scale_shift[COUT + c];
    const float b2c = b2[c];
    float w2c[COUT];
#pragma unroll
    for (int d = 0; d < COUT; ++d) w2c[d] = w2[d * COUT + c];

    const int rowbase = (blockIdx.x * 4 + wv) * 8;

    for (int pair = 0; pair < 4; ++pair) {
        const int ra = rowbase + pair * 2;
#pragma unroll
        for (int rr = 0; rr < 2; ++rr) {
            const int row = ra + rr;
            const int b   = row >> 12;
            const float xi0 = x[row * 3 + 0];
            const float xi1 = x[row * 3 + 1];
            const float xi2 = x[row * 3 + 2];
#pragma unroll
            for (int k = 0; k < KNN; ++k) {
                int j = idx[row * KNN + k];               // wave-uniform
                const float* pj = x + ((size_t)b * N_ + j) * 3;
                float e3 = pj[0] - xi0, e4 = pj[1] - xi1, e5 = pj[2] - xi2;
                float h = b1c;
                h = fmaf(xi0, w1c[0], h); h = fmaf(xi1, w1c[1], h);
                h = fmaf(xi2, w1c[2], h); h = fmaf(e3,  w1c[3], h);
                h = fmaf(e4,  w1c[4], h); h = fmaf(e5,  w1c[5], h);
                h = fmaf(h, sc, sh);
                h2[wv][k][c][rr] = fmaxf(h, 0.0f);        // 2-way bank alias: free
            }
        }
        __syncthreads();   // uniform across the block's 4 waves

        float mxa = -INFINITY, mxb = -INFINITY;
#pragma unroll
        for (int k = 0; k < KNN; ++k) {
            float aa = b2c, ab = b2c;
#pragma unroll
            for (int d2 = 0; d2 < COUT / 2; ++d2) {
                float4 hv = *(const float4*)&h2[wv][k][d2 * 2][0]; // broadcast
                aa = fmaf(hv.x, w2c[d2 * 2 + 0], aa);
                ab = fmaf(hv.y, w2c[d2 * 2 + 0], ab);
                aa = fmaf(hv.z, w2c[d2 * 2 + 1], aa);
                ab = fmaf(hv.w, w2c[d2 * 2 + 1], ab);
            }
            mxa = fmaxf(mxa, aa); mxb = fmaxf(mxb, ab);
        }
        out[(size_t)ra * COUT + c]       = mxa;
        out[(size_t)(ra + 1) * COUT + c] = mxb;
        __syncthreads();   // protect h2 reuse next pair
    }
}

// ===========================================================================
extern "C" void kernel_launch(void* const* d_in, const int* in_sizes, int n_in,
                              void* d_out, int out_size, void* d_ws, size_t ws_size,
                              hipStream_t stream)
{
    const float* x     = (const float*)d_in[0];
    const float* w1    = (const float*)d_in[2];
    const float* b1    = (const float*)d_in[3];
    const float* gamma = (const float*)d_in[4];
    const float* beta  = (const float*)d_in[5];
    const float* w2    = (const float*)d_in[6];
    const float* b2    = (const float*)d_in[7];
    float* out = (float*)d_out;

    char*   ws          = (char*)d_ws;
    double* stats       = (double*)ws;
    float*  scale_shift = (float*)(ws + 256);
    int*    idx         = (int*)(ws + 1024);
    int*    perm        = (int*)(ws + 1024 + (size_t)B_ * N_ * KNN * 4);

    hipMemsetAsync(stats, 0, 27 * sizeof(double), stream);
    morton_bucket_kernel<<<B_, 1024, 0, stream>>>(x, perm);
    knn_f64_kernel<<<dim3(32, 16), 512, 0, stream>>>(x, perm, idx, stats);
    bn_prep_kernel<<<1, COUT, 0, stream>>>(stats, w1, b1, gamma, beta, scale_shift);
    mlp_max_kernel<<<(B_ * N_) / 32, 256, 0, stream>>>(x, idx, w1, b1, scale_shift,
                                                       w2, b2, out);
}